// Round 1
// baseline (463.382 us; speedup 1.0000x reference)
//
#include <hip/hip_runtime.h>
#include <hip/hip_bf16.h>
#include <stdint.h>

typedef __attribute__((ext_vector_type(8))) short bf16x8;
typedef __attribute__((ext_vector_type(4))) float f32x4;
typedef __attribute__((ext_vector_type(4))) int i32x4;

__device__ __forceinline__ short f2bf(float f) {
  uint32_t u = __builtin_bit_cast(uint32_t, f);
  u = u + 0x7FFFu + ((u >> 16) & 1u);
  return (short)(u >> 16);
}

// ---------------- convert / transpose ----------------

__global__ __launch_bounds__(256) void convert_x_kernel(const float* __restrict__ x,
                                                        short* __restrict__ xb) {
  int i = (blockIdx.x * 256 + threadIdx.x) * 8;
  float4 v0 = *(const float4*)(x + i);
  float4 v1 = *(const float4*)(x + i + 4);
  uint32_t p0 = (uint16_t)f2bf(v0.x) | ((uint32_t)(uint16_t)f2bf(v0.y) << 16);
  uint32_t p1 = (uint16_t)f2bf(v0.z) | ((uint32_t)(uint16_t)f2bf(v0.w) << 16);
  uint32_t p2 = (uint16_t)f2bf(v1.x) | ((uint32_t)(uint16_t)f2bf(v1.y) << 16);
  uint32_t p3 = (uint16_t)f2bf(v1.z) | ((uint32_t)(uint16_t)f2bf(v1.w) << 16);
  i32x4 o = {(int)p0, (int)p1, (int)p2, (int)p3};
  *(i32x4*)(xb + i) = o;
}

// W [512][N] fp32 -> Wt [N][512] bf16
__global__ __launch_bounds__(256) void transpose_w_kernel(const float* __restrict__ W,
                                                          short* __restrict__ Wt, int N) {
  int idx = blockIdx.x * 256 + threadIdx.x;   // over N*512
  int n = idx >> 9, k = idx & 511;
  Wt[idx] = f2bf(W[(size_t)k * N + n]);
}

// ---------------- QKV GEMM ----------------
// A [8192][512] bf16, Bt [1536][512] bf16, out scattered to Q/K/Vt

__global__ __launch_bounds__(256) void gemm_qkv_kernel(const short* __restrict__ A,
                                                       const short* __restrict__ Bt,
                                                       const float* __restrict__ bias,
                                                       short* __restrict__ Qb,
                                                       short* __restrict__ Kb,
                                                       short* __restrict__ Vt) {
  __shared__ short Al[128 * 32];
  __shared__ short Bl[128 * 32];
  const int tid = threadIdx.x;
  const int bm = (blockIdx.x & 63) << 7;
  const int bn = (blockIdx.x >> 6) << 7;
  const int lane = tid & 63;
  const int wv = tid >> 6;
  const int wm = (wv >> 1) * 64, wn = (wv & 1) * 64;
  const int lr = lane & 15, lg = lane >> 4;

  f32x4 acc[4][4];
#pragma unroll
  for (int i = 0; i < 4; i++)
#pragma unroll
    for (int j = 0; j < 4; j++) acc[i][j] = (f32x4){0.f, 0.f, 0.f, 0.f};

  for (int k0 = 0; k0 < 512; k0 += 32) {
    __syncthreads();
#pragma unroll
    for (int i = 0; i < 2; ++i) {
      int c = tid + i * 256;
      int row = c >> 2, coff = (c & 3) * 8;
      *(i32x4*)(&Al[row * 32 + coff]) = *(const i32x4*)(A + (size_t)(bm + row) * 512 + k0 + coff);
      *(i32x4*)(&Bl[row * 32 + coff]) = *(const i32x4*)(Bt + (size_t)(bn + row) * 512 + k0 + coff);
    }
    __syncthreads();
    bf16x8 a[4], b[4];
#pragma unroll
    for (int mi = 0; mi < 4; mi++) a[mi] = *(const bf16x8*)(&Al[(wm + mi * 16 + lr) * 32 + lg * 8]);
#pragma unroll
    for (int ni = 0; ni < 4; ni++) b[ni] = *(const bf16x8*)(&Bl[(wn + ni * 16 + lr) * 32 + lg * 8]);
#pragma unroll
    for (int mi = 0; mi < 4; mi++)
#pragma unroll
      for (int ni = 0; ni < 4; ni++)
        acc[mi][ni] = __builtin_amdgcn_mfma_f32_16x16x32_bf16(a[mi], b[ni], acc[mi][ni], 0, 0, 0);
  }

#pragma unroll
  for (int ni = 0; ni < 4; ni++) {
    int n = bn + wn + ni * 16 + lr;
    float bv = bias[n];
    int three = n >> 9, hn = n & 511;
    int h = hn >> 6, d = hn & 63;
#pragma unroll
    for (int mi = 0; mi < 4; mi++) {
#pragma unroll
      for (int r = 0; r < 4; r++) {
        int m = bm + wm + mi * 16 + lg * 4 + r;
        int bb = m >> 12, s = m & 4095;
        float v = acc[mi][ni][r] + bv;
        int bh = bb * 8 + h;
        if (three == 0) {
          Qb[((size_t)bh * 4096 + s) * 64 + d] = f2bf(v * 0.125f);  // exact pre-scale
        } else if (three == 1) {
          Kb[((size_t)bh * 4096 + s) * 64 + d] = f2bf(v);
        } else {
          Vt[((size_t)bh * 64 + d) * 4096 + s] = f2bf(v);
        }
      }
    }
  }
}

// ---------------- flash attention ----------------
// Qb/Kb [bh][4096][64] bf16 (Q pre-scaled), Vt [bh][64][4096] bf16
// Ob [8192][512] bf16 (col = h*64+d)

__global__ __launch_bounds__(256) void attn_kernel(const short* __restrict__ Qb,
                                                   const short* __restrict__ Kb,
                                                   const short* __restrict__ Vt,
                                                   short* __restrict__ Ob) {
  __shared__ short Kl[32 * 64];      // swizzled, 128B rows
  __shared__ short Vl[64 * 40];      // [d][key], stride 40 elems (80B)
  __shared__ short Pl[4 * 16 * 40];  // per-wave [16][40]
  const int tid = threadIdx.x;
  const int lane = tid & 63;
  const int wv = tid >> 6;
  const int lr = lane & 15, lg = lane >> 4;
  const int bh = blockIdx.x >> 6;
  const int qt = blockIdx.x & 63;
  const int qrow = qt * 64 + wv * 16 + lr;

  const size_t qbase = ((size_t)bh * 4096 + qrow) * 64;
  bf16x8 qf0 = *(const bf16x8*)(Qb + qbase + lg * 8);
  bf16x8 qf1 = *(const bf16x8*)(Qb + qbase + 32 + lg * 8);

  float m_run[4], l_run[4];
  f32x4 o[4];
#pragma unroll
  for (int r = 0; r < 4; r++) { m_run[r] = -1e30f; l_run[r] = 0.f; }
#pragma unroll
  for (int nt = 0; nt < 4; nt++) o[nt] = (f32x4){0.f, 0.f, 0.f, 0.f};

  const int kc_row = tid >> 3, kc_off = tid & 7;  // K stage: 256 x 16B
  const int vc_d = tid >> 2, vc_off = tid & 3;    // V stage: 256 x 16B
  const size_t kgbase = (size_t)bh * 4096 * 64;
  const size_t vgbase = (size_t)bh * 64 * 4096;
  short* Plw = Pl + wv * 16 * 40;

  for (int kb = 0; kb < 4096; kb += 32) {
    {
      i32x4 kv = *(const i32x4*)(Kb + kgbase + (size_t)(kb + kc_row) * 64 + kc_off * 8);
      *(i32x4*)((char*)Kl + kc_row * 128 + ((kc_off * 16) ^ ((kc_row & 7) << 4))) = kv;
      i32x4 vv = *(const i32x4*)(Vt + vgbase + (size_t)vc_d * 4096 + kb + vc_off * 8);
      *(i32x4*)((char*)Vl + vc_d * 80 + vc_off * 16) = vv;
    }
    __syncthreads();

    // S = Q @ K^T  (Q pre-scaled by 1/8)
    f32x4 st[2];
#pragma unroll
    for (int kt = 0; kt < 2; kt++) {
      f32x4 s = (f32x4){0.f, 0.f, 0.f, 0.f};
      int key = kt * 16 + lr;
      bf16x8 b0 = *(const bf16x8*)((char*)Kl + key * 128 + ((lg * 16) ^ ((key & 7) << 4)));
      s = __builtin_amdgcn_mfma_f32_16x16x32_bf16(qf0, b0, s, 0, 0, 0);
      bf16x8 b1 = *(const bf16x8*)((char*)Kl + key * 128 + ((64 + lg * 16) ^ ((key & 7) << 4)));
      s = __builtin_amdgcn_mfma_f32_16x16x32_bf16(qf1, b1, s, 0, 0, 0);
      st[kt] = s;
    }

    // online softmax
    float cand[4], fac[4], p0[4], p1[4];
#pragma unroll
    for (int r = 0; r < 4; r++) {
      float c = fmaxf(st[0][r], st[1][r]);
      c = fmaxf(c, __shfl_xor(c, 1, 64));
      c = fmaxf(c, __shfl_xor(c, 2, 64));
      c = fmaxf(c, __shfl_xor(c, 4, 64));
      c = fmaxf(c, __shfl_xor(c, 8, 64));
      cand[r] = c;
    }
#pragma unroll
    for (int r = 0; r < 4; r++) {
      float mn = fmaxf(m_run[r], cand[r]);
      fac[r] = exp2f((m_run[r] - mn) * 1.44269504f);
      p0[r] = exp2f((st[0][r] - mn) * 1.44269504f);
      p1[r] = exp2f((st[1][r] - mn) * 1.44269504f);
      m_run[r] = mn;
      float rsv = p0[r] + p1[r];
      rsv += __shfl_xor(rsv, 1, 64);
      rsv += __shfl_xor(rsv, 2, 64);
      rsv += __shfl_xor(rsv, 4, 64);
      rsv += __shfl_xor(rsv, 8, 64);
      l_run[r] = l_run[r] * fac[r] + rsv;
    }
#pragma unroll
    for (int nt = 0; nt < 4; nt++)
#pragma unroll
      for (int r = 0; r < 4; r++) o[nt][r] *= fac[r];

    // P -> LDS (per-wave), reshape D-layout -> A-layout
#pragma unroll
    for (int r = 0; r < 4; r++) {
      Plw[(lg * 4 + r) * 40 + lr] = f2bf(p0[r]);
      Plw[(lg * 4 + r) * 40 + 16 + lr] = f2bf(p1[r]);
    }
    bf16x8 pf = *(const bf16x8*)(&Plw[lr * 40 + lg * 8]);

    // O += P @ V
#pragma unroll
    for (int nt = 0; nt < 4; nt++) {
      bf16x8 vf = *(const bf16x8*)((char*)Vl + (nt * 16 + lr) * 80 + lg * 16);
      o[nt] = __builtin_amdgcn_mfma_f32_16x16x32_bf16(pf, vf, o[nt], 0, 0, 0);
    }
    __syncthreads();
  }

  const int bb = bh >> 3, h = bh & 7;
#pragma unroll
  for (int r = 0; r < 4; r++) {
    float inv = 1.f / l_run[r];
    int s = qt * 64 + wv * 16 + lg * 4 + r;
    size_t rowb = ((size_t)bb * 4096 + s) * 512 + h * 64;
#pragma unroll
    for (int nt = 0; nt < 4; nt++) Ob[rowb + nt * 16 + lr] = f2bf(o[nt][r] * inv);
  }
}

// ---------------- proj GEMM ----------------

__global__ __launch_bounds__(256) void gemm_proj_kernel(const short* __restrict__ A,
                                                        const short* __restrict__ Bt,
                                                        const float* __restrict__ bias,
                                                        float* __restrict__ out) {
  __shared__ short Al[128 * 32];
  __shared__ short Bl[128 * 32];
  const int tid = threadIdx.x;
  const int bm = (blockIdx.x & 63) << 7;
  const int bn = (blockIdx.x >> 6) << 7;
  const int lane = tid & 63;
  const int wv = tid >> 6;
  const int wm = (wv >> 1) * 64, wn = (wv & 1) * 64;
  const int lr = lane & 15, lg = lane >> 4;

  f32x4 acc[4][4];
#pragma unroll
  for (int i = 0; i < 4; i++)
#pragma unroll
    for (int j = 0; j < 4; j++) acc[i][j] = (f32x4){0.f, 0.f, 0.f, 0.f};

  for (int k0 = 0; k0 < 512; k0 += 32) {
    __syncthreads();
#pragma unroll
    for (int i = 0; i < 2; ++i) {
      int c = tid + i * 256;
      int row = c >> 2, coff = (c & 3) * 8;
      *(i32x4*)(&Al[row * 32 + coff]) = *(const i32x4*)(A + (size_t)(bm + row) * 512 + k0 + coff);
      *(i32x4*)(&Bl[row * 32 + coff]) = *(const i32x4*)(Bt + (size_t)(bn + row) * 512 + k0 + coff);
    }
    __syncthreads();
    bf16x8 a[4], b[4];
#pragma unroll
    for (int mi = 0; mi < 4; mi++) a[mi] = *(const bf16x8*)(&Al[(wm + mi * 16 + lr) * 32 + lg * 8]);
#pragma unroll
    for (int ni = 0; ni < 4; ni++) b[ni] = *(const bf16x8*)(&Bl[(wn + ni * 16 + lr) * 32 + lg * 8]);
#pragma unroll
    for (int mi = 0; mi < 4; mi++)
#pragma unroll
      for (int ni = 0; ni < 4; ni++)
        acc[mi][ni] = __builtin_amdgcn_mfma_f32_16x16x32_bf16(a[mi], b[ni], acc[mi][ni], 0, 0, 0);
  }

#pragma unroll
  for (int ni = 0; ni < 4; ni++) {
    int n = bn + wn + ni * 16 + lr;
    float bv = bias[n];
#pragma unroll
    for (int mi = 0; mi < 4; mi++) {
#pragma unroll
      for (int r = 0; r < 4; r++) {
        int m = bm + wm + mi * 16 + lg * 4 + r;
        out[(size_t)m * 512 + n] = acc[mi][ni][r] + bv;
      }
    }
  }
}

// ---------------- launch ----------------

extern "C" void kernel_launch(void* const* d_in, const int* in_sizes, int n_in,
                              void* d_out, int out_size, void* d_ws, size_t ws_size,
                              hipStream_t stream) {
  const float* x = (const float*)d_in[0];
  const float* Wqkv = (const float*)d_in[1];
  const float* bqkv = (const float*)d_in[2];
  const float* Wproj = (const float*)d_in[3];
  const float* bproj = (const float*)d_in[4];
  float* out = (float*)d_out;

  char* ws = (char*)d_ws;
  short* xb  = (short*)(ws);                          // 8192*512*2      = 8388608
  short* Wqt = (short*)(ws + 8388608);                // 1536*512*2      = 1572864
  short* Wpt = (short*)(ws + 9961472);                // 512*512*2       = 524288
  short* Qb  = (short*)(ws + 10485760);               // 16*4096*64*2    = 8388608
  short* Kb  = (short*)(ws + 18874368);               // 8388608
  short* Vt  = (short*)(ws + 27262976);               // 8388608
  short* Ob  = (short*)(ws + 35651584);               // 8388608  (total 44040192)

  convert_x_kernel<<<2048, 256, 0, stream>>>(x, xb);
  transpose_w_kernel<<<3072, 256, 0, stream>>>(Wqkv, Wqt, 1536);
  transpose_w_kernel<<<1024, 256, 0, stream>>>(Wproj, Wpt, 512);
  gemm_qkv_kernel<<<768, 256, 0, stream>>>(xb, Wqt, bqkv, Qb, Kb, Vt);
  attn_kernel<<<1024, 256, 0, stream>>>(Qb, Kb, Vt, Ob);
  gemm_proj_kernel<<<256, 256, 0, stream>>>(Ob, Wpt, bproj, out);
}

// Round 3
// 281.337 us; speedup vs baseline: 1.6471x; 1.6471x over previous
//
#include <hip/hip_runtime.h>
#include <hip/hip_bf16.h>
#include <stdint.h>

typedef __attribute__((ext_vector_type(8))) short bf16x8;
typedef __attribute__((ext_vector_type(4))) float f32x4;
typedef __attribute__((ext_vector_type(4))) int i32x4;

__device__ __forceinline__ short f2bf(float f) {
  uint32_t u = __builtin_bit_cast(uint32_t, f);
  u = u + 0x7FFFu + ((u >> 16) & 1u);
  return (short)(u >> 16);
}

// ---------------- convert / transpose ----------------

__global__ __launch_bounds__(256) void convert_x_kernel(const float* __restrict__ x,
                                                        short* __restrict__ xb) {
  int i = (blockIdx.x * 256 + threadIdx.x) * 8;
  float4 v0 = *(const float4*)(x + i);
  float4 v1 = *(const float4*)(x + i + 4);
  uint32_t p0 = (uint16_t)f2bf(v0.x) | ((uint32_t)(uint16_t)f2bf(v0.y) << 16);
  uint32_t p1 = (uint16_t)f2bf(v0.z) | ((uint32_t)(uint16_t)f2bf(v0.w) << 16);
  uint32_t p2 = (uint16_t)f2bf(v1.x) | ((uint32_t)(uint16_t)f2bf(v1.y) << 16);
  uint32_t p3 = (uint16_t)f2bf(v1.z) | ((uint32_t)(uint16_t)f2bf(v1.w) << 16);
  i32x4 o = {(int)p0, (int)p1, (int)p2, (int)p3};
  *(i32x4*)(xb + i) = o;
}

// W [512][N] fp32 -> Wt [N][512] bf16
__global__ __launch_bounds__(256) void transpose_w_kernel(const float* __restrict__ W,
                                                          short* __restrict__ Wt, int N) {
  int idx = blockIdx.x * 256 + threadIdx.x;   // over N*512
  int n = idx >> 9, k = idx & 511;
  Wt[idx] = f2bf(W[(size_t)k * N + n]);
}

// ---------------- QKV GEMM ----------------
// A [8192][512] bf16, Bt [1536][512] bf16, out scattered to Q/K/Vt

__global__ __launch_bounds__(256) void gemm_qkv_kernel(const short* __restrict__ A,
                                                       const short* __restrict__ Bt,
                                                       const float* __restrict__ bias,
                                                       short* __restrict__ Qb,
                                                       short* __restrict__ Kb,
                                                       short* __restrict__ Vt) {
  __shared__ short Al[128 * 32];
  __shared__ short Bl[128 * 32];
  const int tid = threadIdx.x;
  const int bm = (blockIdx.x & 63) << 7;
  const int bn = (blockIdx.x >> 6) << 7;
  const int lane = tid & 63;
  const int wv = tid >> 6;
  const int wm = (wv >> 1) * 64, wn = (wv & 1) * 64;
  const int lr = lane & 15, lg = lane >> 4;

  f32x4 acc[4][4];
#pragma unroll
  for (int i = 0; i < 4; i++)
#pragma unroll
    for (int j = 0; j < 4; j++) acc[i][j] = (f32x4){0.f, 0.f, 0.f, 0.f};

  for (int k0 = 0; k0 < 512; k0 += 32) {
    __syncthreads();
#pragma unroll
    for (int i = 0; i < 2; ++i) {
      int c = tid + i * 256;
      int row = c >> 2, coff = (c & 3) * 8;
      *(i32x4*)(&Al[row * 32 + coff]) = *(const i32x4*)(A + (size_t)(bm + row) * 512 + k0 + coff);
      *(i32x4*)(&Bl[row * 32 + coff]) = *(const i32x4*)(Bt + (size_t)(bn + row) * 512 + k0 + coff);
    }
    __syncthreads();
    bf16x8 a[4], b[4];
#pragma unroll
    for (int mi = 0; mi < 4; mi++) a[mi] = *(const bf16x8*)(&Al[(wm + mi * 16 + lr) * 32 + lg * 8]);
#pragma unroll
    for (int ni = 0; ni < 4; ni++) b[ni] = *(const bf16x8*)(&Bl[(wn + ni * 16 + lr) * 32 + lg * 8]);
#pragma unroll
    for (int mi = 0; mi < 4; mi++)
#pragma unroll
      for (int ni = 0; ni < 4; ni++)
        acc[mi][ni] = __builtin_amdgcn_mfma_f32_16x16x32_bf16(a[mi], b[ni], acc[mi][ni], 0, 0, 0);
  }

#pragma unroll
  for (int ni = 0; ni < 4; ni++) {
    int n = bn + wn + ni * 16 + lr;
    float bv = bias[n];
    int three = n >> 9, hn = n & 511;
    int h = hn >> 6, d = hn & 63;
#pragma unroll
    for (int mi = 0; mi < 4; mi++) {
#pragma unroll
      for (int r = 0; r < 4; r++) {
        int m = bm + wm + mi * 16 + lg * 4 + r;
        int bb = m >> 12, s = m & 4095;
        float v = acc[mi][ni][r] + bv;
        int bh = bb * 8 + h;
        if (three == 0) {
          Qb[((size_t)bh * 4096 + s) * 64 + d] = f2bf(v * 0.125f);  // exact pre-scale
        } else if (three == 1) {
          Kb[((size_t)bh * 4096 + s) * 64 + d] = f2bf(v);
        } else {
          Vt[((size_t)bh * 64 + d) * 4096 + s] = f2bf(v);
        }
      }
    }
  }
}

// ---------------- flash attention ----------------
// Qb/Kb [bh][4096][64] bf16 (Q pre-scaled), Vt [bh][64][4096] bf16
// Ob [8192][512] bf16 (col = h*64+d)
// KBLK=64, double-buffered global_load_lds staging with XOR 16B-chunk swizzle.

__global__ __launch_bounds__(256, 4) void attn_kernel(const short* __restrict__ Qb,
                                                      const short* __restrict__ Kb,
                                                      const short* __restrict__ Vt,
                                                      short* __restrict__ Ob) {
  __shared__ short Kl[2][64 * 64];  // [key row][8 x 16B chunks, pos = chunk^(row&7)]
  __shared__ short Vl[2][64 * 64];  // [d row][8 x 16B chunks of keys, pos = chunk^(row&7)]
  __shared__ short Pl[4][16 * 64];  // per-wave [q row][64 keys], chunk-swizzled

  const int tid = threadIdx.x;
  const int lane = tid & 63;
  const int wv = tid >> 6;
  const int lr = lane & 15, lg = lane >> 4;
  // XCD-aware swizzle: blocks of head-pair (h, h+8) all land on XCD h (b%8).
  const int b = blockIdx.x;
  const int qt = (b >> 3) & 63;
  const int bh = (b & 7) | ((b >> 9) << 3);

  const int qrow = qt * 64 + wv * 16 + lr;
  const size_t qbase = ((size_t)bh * 4096 + qrow) * 64;
  const bf16x8 qf0 = *(const bf16x8*)(Qb + qbase + lg * 8);
  const bf16x8 qf1 = *(const bf16x8*)(Qb + qbase + 32 + lg * 8);

  const short one_bf = (short)0x3F80;
  const bf16x8 onesf = {one_bf, one_bf, one_bf, one_bf, one_bf, one_bf, one_bf, one_bf};

  float m_run = -1e30f;
  f32x4 ol = (f32x4){0.f, 0.f, 0.f, 0.f};
  f32x4 o[4];
#pragma unroll
  for (int nt = 0; nt < 4; nt++) o[nt] = (f32x4){0.f, 0.f, 0.f, 0.f};

  const size_t kgbase = (size_t)bh * 4096 * 64;
  const size_t vgbase = (size_t)bh * 64 * 4096;
  short* Pw = &Pl[wv][0];

  // staging geometry: 8 wave-loads of 1KB each cover 64 rows x 128B.
  const int srow = lane >> 3;                 // row within the 8-row group
  const int schunk = ((lane & 7) ^ srow) * 8; // pre-swizzled source chunk (elems)
  const int li0 = wv * 2;

  auto stage = [&](int buf, int kb_) {
#pragma unroll
    for (int i = 0; i < 2; i++) {
      const int li = li0 + i;
      const int row = li * 8 + srow;
      __builtin_amdgcn_global_load_lds(
          (const __attribute__((address_space(1))) void*)(Kb + kgbase + (size_t)(kb_ + row) * 64 + schunk),
          (__attribute__((address_space(3))) void*)(&Kl[buf][li * 512]), 16, 0, 0);
      __builtin_amdgcn_global_load_lds(
          (const __attribute__((address_space(1))) void*)(Vt + vgbase + (size_t)row * 4096 + kb_ + schunk),
          (__attribute__((address_space(3))) void*)(&Vl[buf][li * 512]), 16, 0, 0);
    }
  };

  stage(0, 0);
  __syncthreads();
  int cur = 0;

  for (int kb = 0; kb < 4096; kb += 64) {
    if (kb + 64 < 4096) stage(cur ^ 1, kb + 64);

    const short* Kc = &Kl[cur][0];
    const short* Vc = &Vl[cur][0];
    const int sw = (lr & 7) << 4;

    // S = Q @ K^T  (Q pre-scaled by 1/8); st[kt]: q row = lg*4+r, key = kt*16+lr
    f32x4 st[4];
#pragma unroll
    for (int kt = 0; kt < 4; kt++) {
      const int key = kt * 16 + lr;
      const char* krow = (const char*)Kc + key * 128;
      bf16x8 b0 = *(const bf16x8*)(krow + ((lg * 16) ^ sw));
      bf16x8 b1 = *(const bf16x8*)(krow + ((64 + lg * 16) ^ sw));
      f32x4 s = (f32x4){0.f, 0.f, 0.f, 0.f};
      s = __builtin_amdgcn_mfma_f32_16x16x32_bf16(qf0, b0, s, 0, 0, 0);
      s = __builtin_amdgcn_mfma_f32_16x16x32_bf16(qf1, b1, s, 0, 0, 0);
      st[kt] = s;
    }

    // wave-uniform tile max (valid upper bound for every row; consistent per row)
    float cm = fmaxf(fmaxf(st[0][0], st[0][1]), fmaxf(st[0][2], st[0][3]));
#pragma unroll
    for (int kt = 1; kt < 4; kt++)
      cm = fmaxf(cm, fmaxf(fmaxf(st[kt][0], st[kt][1]), fmaxf(st[kt][2], st[kt][3])));
#pragma unroll
    for (int off = 1; off < 64; off <<= 1) cm = fmaxf(cm, __shfl_xor(cm, off, 64));

    if (cm > m_run) {  // wave-uniform branch; rare after warm-up
      float fac = exp2f((m_run - cm) * 1.44269504f);
      m_run = cm;
#pragma unroll
      for (int nt = 0; nt < 4; nt++)
#pragma unroll
        for (int r = 0; r < 4; r++) o[nt][r] *= fac;
#pragma unroll
      for (int r = 0; r < 4; r++) ol[r] *= fac;
    }
    const float mb = m_run * 1.44269504f;

    // P = exp(S - m), write bf16 to per-wave LDS (chunk-swizzled rows)
#pragma unroll
    for (int kt = 0; kt < 4; kt++)
#pragma unroll
      for (int r = 0; r < 4; r++) {
        float p = exp2f(__builtin_fmaf(st[kt][r], 1.44269504f, -mb));
        const int R = lg * 4 + r;
        const int pos = (kt * 2 + (lr >> 3)) ^ (R & 7);
        Pw[R * 64 + pos * 8 + (lr & 7)] = f2bf(p);
      }

    // A-frags of P (row = lr, 8 consecutive keys per k-slot)
    bf16x8 pf0 = *(const bf16x8*)(Pw + lr * 64 + ((lg ^ (lr & 7)) * 8));
    bf16x8 pf1 = *(const bf16x8*)(Pw + lr * 64 + (((4 + lg) ^ (lr & 7)) * 8));

    // O += P @ V ; l via ones-MFMA (row-sum of P, all cols equal)
#pragma unroll
    for (int nt = 0; nt < 4; nt++) {
      const int d = nt * 16 + lr;
      const char* vrow = (const char*)Vc + d * 128;
      bf16x8 v0 = *(const bf16x8*)(vrow + ((lg * 16) ^ sw));
      bf16x8 v1 = *(const bf16x8*)(vrow + ((64 + lg * 16) ^ sw));
      o[nt] = __builtin_amdgcn_mfma_f32_16x16x32_bf16(pf0, v0, o[nt], 0, 0, 0);
      o[nt] = __builtin_amdgcn_mfma_f32_16x16x32_bf16(pf1, v1, o[nt], 0, 0, 0);
    }
    ol = __builtin_amdgcn_mfma_f32_16x16x32_bf16(pf0, onesf, ol, 0, 0, 0);
    ol = __builtin_amdgcn_mfma_f32_16x16x32_bf16(pf1, onesf, ol, 0, 0, 0);

    __syncthreads();  // next buffer staged (vmcnt drained) + all reads of cur done
    cur ^= 1;
  }

  const int bb = bh >> 3, h = bh & 7;
#pragma unroll
  for (int r = 0; r < 4; r++) {
    float inv = 1.f / ol[r];
    int s = qt * 64 + wv * 16 + lg * 4 + r;
    size_t rowb = ((size_t)bb * 4096 + s) * 512 + h * 64;
#pragma unroll
    for (int nt = 0; nt < 4; nt++) Ob[rowb + nt * 16 + lr] = f2bf(o[nt][r] * inv);
  }
}

// ---------------- proj GEMM ----------------

__global__ __launch_bounds__(256) void gemm_proj_kernel(const short* __restrict__ A,
                                                        const short* __restrict__ Bt,
                                                        const float* __restrict__ bias,
                                                        float* __restrict__ out) {
  __shared__ short Al[128 * 32];
  __shared__ short Bl[128 * 32];
  const int tid = threadIdx.x;
  const int bm = (blockIdx.x & 63) << 7;
  const int bn = (blockIdx.x >> 6) << 7;
  const int lane = tid & 63;
  const int wv = tid >> 6;
  const int wm = (wv >> 1) * 64, wn = (wv & 1) * 64;
  const int lr = lane & 15, lg = lane >> 4;

  f32x4 acc[4][4];
#pragma unroll
  for (int i = 0; i < 4; i++)
#pragma unroll
    for (int j = 0; j < 4; j++) acc[i][j] = (f32x4){0.f, 0.f, 0.f, 0.f};

  for (int k0 = 0; k0 < 512; k0 += 32) {
    __syncthreads();
#pragma unroll
    for (int i = 0; i < 2; ++i) {
      int c = tid + i * 256;
      int row = c >> 2, coff = (c & 3) * 8;
      *(i32x4*)(&Al[row * 32 + coff]) = *(const i32x4*)(A + (size_t)(bm + row) * 512 + k0 + coff);
      *(i32x4*)(&Bl[row * 32 + coff]) = *(const i32x4*)(Bt + (size_t)(bn + row) * 512 + k0 + coff);
    }
    __syncthreads();
    bf16x8 a[4], b[4];
#pragma unroll
    for (int mi = 0; mi < 4; mi++) a[mi] = *(const bf16x8*)(&Al[(wm + mi * 16 + lr) * 32 + lg * 8]);
#pragma unroll
    for (int ni = 0; ni < 4; ni++) b[ni] = *(const bf16x8*)(&Bl[(wn + ni * 16 + lr) * 32 + lg * 8]);
#pragma unroll
    for (int mi = 0; mi < 4; mi++)
#pragma unroll
      for (int ni = 0; ni < 4; ni++)
        acc[mi][ni] = __builtin_amdgcn_mfma_f32_16x16x32_bf16(a[mi], b[ni], acc[mi][ni], 0, 0, 0);
  }

#pragma unroll
  for (int ni = 0; ni < 4; ni++) {
    int n = bn + wn + ni * 16 + lr;
    float bv = bias[n];
#pragma unroll
    for (int mi = 0; mi < 4; mi++) {
#pragma unroll
      for (int r = 0; r < 4; r++) {
        int m = bm + wm + mi * 16 + lg * 4 + r;
        out[(size_t)m * 512 + n] = acc[mi][ni][r] + bv;
      }
    }
  }
}

// ---------------- launch ----------------

extern "C" void kernel_launch(void* const* d_in, const int* in_sizes, int n_in,
                              void* d_out, int out_size, void* d_ws, size_t ws_size,
                              hipStream_t stream) {
  const float* x = (const float*)d_in[0];
  const float* Wqkv = (const float*)d_in[1];
  const float* bqkv = (const float*)d_in[2];
  const float* Wproj = (const float*)d_in[3];
  const float* bproj = (const float*)d_in[4];
  float* out = (float*)d_out;

  char* ws = (char*)d_ws;
  short* xb  = (short*)(ws);                          // 8192*512*2      = 8388608
  short* Wqt = (short*)(ws + 8388608);                // 1536*512*2      = 1572864
  short* Wpt = (short*)(ws + 9961472);                // 512*512*2       = 524288
  short* Qb  = (short*)(ws + 10485760);               // 16*4096*64*2    = 8388608
  short* Kb  = (short*)(ws + 18874368);               // 8388608
  short* Vt  = (short*)(ws + 27262976);               // 8388608
  short* Ob  = (short*)(ws + 35651584);               // 8388608  (total 44040192)

  convert_x_kernel<<<2048, 256, 0, stream>>>(x, xb);
  transpose_w_kernel<<<3072, 256, 0, stream>>>(Wqkv, Wqt, 1536);
  transpose_w_kernel<<<1024, 256, 0, stream>>>(Wproj, Wpt, 512);
  gemm_qkv_kernel<<<768, 256, 0, stream>>>(xb, Wqt, bqkv, Qb, Kb, Vt);
  attn_kernel<<<1024, 256, 0, stream>>>(Qb, Kb, Vt, Ob);
  gemm_proj_kernel<<<256, 256, 0, stream>>>(Ob, Wpt, bproj, out);
}

// Round 4
// 256.202 us; speedup vs baseline: 1.8087x; 1.0981x over previous
//
#include <hip/hip_runtime.h>
#include <hip/hip_bf16.h>
#include <stdint.h>

typedef __attribute__((ext_vector_type(8))) short bf16x8;
typedef __attribute__((ext_vector_type(4))) float f32x4;
typedef __attribute__((ext_vector_type(16))) float f32x16;
typedef __attribute__((ext_vector_type(4))) int i32x4;

__device__ __forceinline__ short f2bf(float f) {
  uint32_t u = __builtin_bit_cast(uint32_t, f);
  u = u + 0x7FFFu + ((u >> 16) & 1u);
  return (short)(u >> 16);
}

// ---------------- convert / transpose ----------------

__global__ __launch_bounds__(256) void convert_x_kernel(const float* __restrict__ x,
                                                        short* __restrict__ xb) {
  int i = (blockIdx.x * 256 + threadIdx.x) * 8;
  float4 v0 = *(const float4*)(x + i);
  float4 v1 = *(const float4*)(x + i + 4);
  uint32_t p0 = (uint16_t)f2bf(v0.x) | ((uint32_t)(uint16_t)f2bf(v0.y) << 16);
  uint32_t p1 = (uint16_t)f2bf(v0.z) | ((uint32_t)(uint16_t)f2bf(v0.w) << 16);
  uint32_t p2 = (uint16_t)f2bf(v1.x) | ((uint32_t)(uint16_t)f2bf(v1.y) << 16);
  uint32_t p3 = (uint16_t)f2bf(v1.z) | ((uint32_t)(uint16_t)f2bf(v1.w) << 16);
  i32x4 o = {(int)p0, (int)p1, (int)p2, (int)p3};
  *(i32x4*)(xb + i) = o;
}

// W [512][N] fp32 -> Wt [N][512] bf16, LDS-tiled 64x64 (coalesced both sides)
__global__ __launch_bounds__(256) void transpose_w_kernel(const float* __restrict__ W,
                                                          short* __restrict__ Wt, int N,
                                                          int nTilesN) {
  __shared__ short Ts[64 * 66];
  const int t = threadIdx.x;
  const int n0 = (blockIdx.x % nTilesN) * 64;
  const int k0 = (blockIdx.x / nTilesN) * 64;
#pragma unroll
  for (int j = 0; j < 16; j++) {
    int e = j * 256 + t;
    int k = e >> 6, n = e & 63;
    Ts[k * 66 + n] = f2bf(W[(size_t)(k0 + k) * N + n0 + n]);
  }
  __syncthreads();
#pragma unroll
  for (int j = 0; j < 16; j++) {
    int e = j * 256 + t;
    int n = e >> 6, k = e & 63;
    Wt[(size_t)(n0 + n) * 512 + k0 + k] = Ts[k * 66 + n];
  }
}

// ---------------- QKV GEMM ----------------
// A [8192][512] bf16, Bt [1536][512] bf16, out scattered to Q/K/Vt

__global__ __launch_bounds__(256) void gemm_qkv_kernel(const short* __restrict__ A,
                                                       const short* __restrict__ Bt,
                                                       const float* __restrict__ bias,
                                                       short* __restrict__ Qb,
                                                       short* __restrict__ Kb,
                                                       short* __restrict__ Vt) {
  __shared__ short Al[128 * 32];
  __shared__ short Bl[128 * 32];
  const int tid = threadIdx.x;
  const int bm = (blockIdx.x & 63) << 7;
  const int bn = (blockIdx.x >> 6) << 7;
  const int lane = tid & 63;
  const int wv = tid >> 6;
  const int wm = (wv >> 1) * 64, wn = (wv & 1) * 64;
  const int lr = lane & 15, lg = lane >> 4;

  f32x4 acc[4][4];
#pragma unroll
  for (int i = 0; i < 4; i++)
#pragma unroll
    for (int j = 0; j < 4; j++) acc[i][j] = (f32x4){0.f, 0.f, 0.f, 0.f};

  for (int k0 = 0; k0 < 512; k0 += 32) {
    __syncthreads();
#pragma unroll
    for (int i = 0; i < 2; ++i) {
      int c = tid + i * 256;
      int row = c >> 2, coff = (c & 3) * 8;
      __builtin_amdgcn_global_load_lds(
          (const __attribute__((address_space(1))) void*)(A + (size_t)(bm + row) * 512 + k0 + coff),
          (__attribute__((address_space(3))) void*)(&Al[c * 8]), 16, 0, 0);
      __builtin_amdgcn_global_load_lds(
          (const __attribute__((address_space(1))) void*)(Bt + (size_t)(bn + row) * 512 + k0 + coff),
          (__attribute__((address_space(3))) void*)(&Bl[c * 8]), 16, 0, 0);
    }
    __syncthreads();
    bf16x8 a[4], b[4];
#pragma unroll
    for (int mi = 0; mi < 4; mi++) a[mi] = *(const bf16x8*)(&Al[(wm + mi * 16 + lr) * 32 + lg * 8]);
#pragma unroll
    for (int ni = 0; ni < 4; ni++) b[ni] = *(const bf16x8*)(&Bl[(wn + ni * 16 + lr) * 32 + lg * 8]);
#pragma unroll
    for (int mi = 0; mi < 4; mi++)
#pragma unroll
      for (int ni = 0; ni < 4; ni++)
        acc[mi][ni] = __builtin_amdgcn_mfma_f32_16x16x32_bf16(a[mi], b[ni], acc[mi][ni], 0, 0, 0);
  }

#pragma unroll
  for (int ni = 0; ni < 4; ni++) {
    int n = bn + wn + ni * 16 + lr;
    float bv = bias[n];
    int three = n >> 9, hn = n & 511;
    int h = hn >> 6, d = hn & 63;
#pragma unroll
    for (int mi = 0; mi < 4; mi++) {
#pragma unroll
      for (int r = 0; r < 4; r++) {
        int m = bm + wm + mi * 16 + lg * 4 + r;
        int bb = m >> 12, s = m & 4095;
        float v = acc[mi][ni][r] + bv;
        int bh = bb * 8 + h;
        if (three == 0) {
          Qb[((size_t)bh * 4096 + s) * 64 + d] = f2bf(v * 0.125f);  // exact pre-scale
        } else if (three == 1) {
          Kb[((size_t)bh * 4096 + s) * 64 + d] = f2bf(v);
        } else {
          Vt[((size_t)bh * 64 + d) * 4096 + s] = f2bf(v);
        }
      }
    }
  }
}

// ---------------- flash attention ----------------
// Qb/Kb [bh][4096][64] bf16 (Q pre-scaled), Vt [bh][64][4096] bf16
// Ob [8192][512] bf16 (col = h*64+d)
// 32x32x16 MFMA, swapped QK^T (S^T), P in registers via cvt_pk + shfl_xor(32).
// 4 waves x 32 q-rows = 128 q/block; 512 blocks; KBLK=64 dbuf global_load_lds.

__global__ __launch_bounds__(256, 2) void attn_kernel(const short* __restrict__ Qb,
                                                      const short* __restrict__ Kb,
                                                      const short* __restrict__ Vt,
                                                      short* __restrict__ Ob) {
  __shared__ short Kl[2][64 * 64];  // [key][8 x 16B chunks, pos = chunk^(key&7)]
  __shared__ short Vl[2][64 * 64];  // [d][8 x 16B chunks of keys, pos = chunk^(d&7)]

  const int tid = threadIdx.x;
  const int lane = tid & 63;
  const int wv = tid >> 6;
  const int q5 = lane & 31, h = lane >> 5;
  // XCD swizzle: head pair (hh, hh+8) on XCD hh.
  const int b = blockIdx.x;
  const int qt = (b >> 3) & 31;
  const int bh = (b & 7) | ((b >> 8) << 3);

  const int qrow = qt * 128 + wv * 32 + q5;
  const short* Qrow = Qb + ((size_t)bh * 4096 + qrow) * 64;
  bf16x8 qf[4];
#pragma unroll
  for (int c = 0; c < 4; c++) qf[c] = *(const bf16x8*)(Qrow + c * 16 + h * 8);

  float m_run = -1e30f, l_run = 0.f;
  f32x16 oA, oB;
#pragma unroll
  for (int r = 0; r < 16; r++) { oA[r] = 0.f; oB[r] = 0.f; }

  const size_t kgbase = (size_t)bh * 4096 * 64;
  const size_t vgbase = (size_t)bh * 64 * 4096;

  // staging: 64 rows x 128B each for K and V; per wave 2+2 loads of 1KB.
  const int srow = lane >> 3;
  const int schunk = ((lane & 7) ^ srow) * 8;
  const int li0 = wv * 2;

  auto stage = [&](int buf, int kb_) {
#pragma unroll
    for (int i = 0; i < 2; i++) {
      const int li = li0 + i;
      const int row = li * 8 + srow;
      __builtin_amdgcn_global_load_lds(
          (const __attribute__((address_space(1))) void*)(Kb + kgbase + (size_t)(kb_ + row) * 64 + schunk),
          (__attribute__((address_space(3))) void*)(&Kl[buf][li * 512]), 16, 0, 0);
      __builtin_amdgcn_global_load_lds(
          (const __attribute__((address_space(1))) void*)(Vt + vgbase + (size_t)row * 4096 + kb_ + schunk),
          (__attribute__((address_space(3))) void*)(&Vl[buf][li * 512]), 16, 0, 0);
    }
  };

  stage(0, 0);
  __syncthreads();
  int cur = 0;

  const int vsw = (q5 & 7) << 4;

  for (int kb = 0; kb < 4096; kb += 64) {
    if (kb + 64 < 4096) stage(cur ^ 1, kb + 64);
    const short* Kc = &Kl[cur][0];
    const short* Vc = &Vl[cur][0];

#pragma unroll
    for (int ks = 0; ks < 2; ks++) {
      // ---- S^T = K @ Q^T : D[key][q], lane: q=q5, keys qmap(r)+4h (+ks*32)
      f32x16 sc;
#pragma unroll
      for (int r = 0; r < 16; r++) sc[r] = 0.f;
      {
        const int krow = ks * 32 + q5;
        const char* kbase = (const char*)Kc + krow * 128;
        const int ksw = (krow & 7) << 4;
#pragma unroll
        for (int c = 0; c < 4; c++) {
          bf16x8 kf = *(const bf16x8*)(kbase + ((((c << 1) + h) << 4) ^ ksw));
          sc = __builtin_amdgcn_mfma_f32_32x32x16_bf16(kf, qf[c], sc, 0, 0, 0);
        }
      }

      // ---- per-row max (q = q5 lives in lanes q5 and q5+32)
      float pm = sc[0];
#pragma unroll
      for (int r = 1; r < 16; r++) pm = fmaxf(pm, sc[r]);
      pm = fmaxf(pm, __shfl_xor(pm, 32, 64));

      // ---- deferred rescale (wave-uniform trigger, per-lane factor)
      if (!__all(pm <= m_run + 8.0f)) {
        float nm = fmaxf(m_run, pm);
        float fac = exp2f((m_run - nm) * 1.44269504f);
        m_run = nm;
        l_run *= fac;
#pragma unroll
        for (int r = 0; r < 16; r++) {
          const int qm = (r & 3) + 8 * (r >> 2);
          float fr = __shfl(fac, qm + (h << 2), 64);
          oA[r] *= fr;
          oB[r] *= fr;
        }
      }

      // ---- P = exp(S - m), row-sum in f32
      const float mb = m_run * 1.44269504f;
      float p[16];
      float ls = 0.f;
#pragma unroll
      for (int r = 0; r < 16; r++) {
        p[r] = exp2f(__builtin_fmaf(sc[r], 1.44269504f, -mb));
        ls += p[r];
      }
      ls += __shfl_xor(ls, 32, 64);
      l_run += ls;

      // ---- pack P to bf16 pairs and exchange halves -> A-frags (T12)
      uint32_t w0, w1, w2, w3, w4, w5, w6, w7;
      asm("v_cvt_pk_bf16_f32 %0, %1, %2" : "=v"(w0) : "v"(p[0]), "v"(p[1]));
      asm("v_cvt_pk_bf16_f32 %0, %1, %2" : "=v"(w1) : "v"(p[2]), "v"(p[3]));
      asm("v_cvt_pk_bf16_f32 %0, %1, %2" : "=v"(w2) : "v"(p[4]), "v"(p[5]));
      asm("v_cvt_pk_bf16_f32 %0, %1, %2" : "=v"(w3) : "v"(p[6]), "v"(p[7]));
      asm("v_cvt_pk_bf16_f32 %0, %1, %2" : "=v"(w4) : "v"(p[8]), "v"(p[9]));
      asm("v_cvt_pk_bf16_f32 %0, %1, %2" : "=v"(w5) : "v"(p[10]), "v"(p[11]));
      asm("v_cvt_pk_bf16_f32 %0, %1, %2" : "=v"(w6) : "v"(p[12]), "v"(p[13]));
      asm("v_cvt_pk_bf16_f32 %0, %1, %2" : "=v"(w7) : "v"(p[14]), "v"(p[15]));
      uint32_t e0 = (uint32_t)__shfl_xor((int)(h ? w0 : w2), 32, 64);
      uint32_t e1 = (uint32_t)__shfl_xor((int)(h ? w1 : w3), 32, 64);
      uint32_t e2 = (uint32_t)__shfl_xor((int)(h ? w4 : w6), 32, 64);
      uint32_t e3 = (uint32_t)__shfl_xor((int)(h ? w5 : w7), 32, 64);
      i32x4 fa0 = {(int)(h ? e0 : w0), (int)(h ? e1 : w1), (int)(h ? w2 : e0), (int)(h ? w3 : e1)};
      i32x4 fa1 = {(int)(h ? e2 : w4), (int)(h ? e3 : w5), (int)(h ? w6 : e2), (int)(h ? w7 : e3)};
      bf16x8 pa0 = __builtin_bit_cast(bf16x8, fa0);
      bf16x8 pa1 = __builtin_bit_cast(bf16x8, fa1);

      // ---- O += P @ V  (A=P rows=q, B=V cols=d)
      {
        const char* vb0 = (const char*)Vc + q5 * 128;
        const char* vb1 = vb0 + 32 * 128;
        const int c0 = ((ks * 4 + h) << 4) ^ vsw;
        const int c1 = ((ks * 4 + 2 + h) << 4) ^ vsw;
        bf16x8 va00 = *(const bf16x8*)(vb0 + c0);
        bf16x8 va01 = *(const bf16x8*)(vb0 + c1);
        bf16x8 va10 = *(const bf16x8*)(vb1 + c0);
        bf16x8 va11 = *(const bf16x8*)(vb1 + c1);
        oA = __builtin_amdgcn_mfma_f32_32x32x16_bf16(pa0, va00, oA, 0, 0, 0);
        oA = __builtin_amdgcn_mfma_f32_32x32x16_bf16(pa1, va01, oA, 0, 0, 0);
        oB = __builtin_amdgcn_mfma_f32_32x32x16_bf16(pa0, va10, oB, 0, 0, 0);
        oB = __builtin_amdgcn_mfma_f32_32x32x16_bf16(pa1, va11, oB, 0, 0, 0);
      }
    }

    __syncthreads();  // staged loads drained + all reads of cur done
    cur ^= 1;
  }

  // ---- epilogue: divide by l (state lives in lane qm+4h), store bf16
  const int bb = bh >> 3, hh = bh & 7;
  float linv = 1.0f / l_run;
#pragma unroll
  for (int r = 0; r < 16; r++) {
    const int qm = (r & 3) + 8 * (r >> 2);
    float li = __shfl(linv, qm + (h << 2), 64);
    int orow = qt * 128 + wv * 32 + qm + 4 * h;
    size_t rowb = ((size_t)bb * 4096 + orow) * 512 + hh * 64;
    Ob[rowb + q5] = f2bf(oA[r] * li);
    Ob[rowb + 32 + q5] = f2bf(oB[r] * li);
  }
}

// ---------------- proj GEMM ----------------

__global__ __launch_bounds__(256) void gemm_proj_kernel(const short* __restrict__ A,
                                                        const short* __restrict__ Bt,
                                                        const float* __restrict__ bias,
                                                        float* __restrict__ out) {
  __shared__ short Al[128 * 32];
  __shared__ short Bl[128 * 32];
  const int tid = threadIdx.x;
  const int bm = (blockIdx.x & 63) << 7;
  const int bn = (blockIdx.x >> 6) << 7;
  const int lane = tid & 63;
  const int wv = tid >> 6;
  const int wm = (wv >> 1) * 64, wn = (wv & 1) * 64;
  const int lr = lane & 15, lg = lane >> 4;

  f32x4 acc[4][4];
#pragma unroll
  for (int i = 0; i < 4; i++)
#pragma unroll
    for (int j = 0; j < 4; j++) acc[i][j] = (f32x4){0.f, 0.f, 0.f, 0.f};

  for (int k0 = 0; k0 < 512; k0 += 32) {
    __syncthreads();
#pragma unroll
    for (int i = 0; i < 2; ++i) {
      int c = tid + i * 256;
      int row = c >> 2, coff = (c & 3) * 8;
      __builtin_amdgcn_global_load_lds(
          (const __attribute__((address_space(1))) void*)(A + (size_t)(bm + row) * 512 + k0 + coff),
          (__attribute__((address_space(3))) void*)(&Al[c * 8]), 16, 0, 0);
      __builtin_amdgcn_global_load_lds(
          (const __attribute__((address_space(1))) void*)(Bt + (size_t)(bn + row) * 512 + k0 + coff),
          (__attribute__((address_space(3))) void*)(&Bl[c * 8]), 16, 0, 0);
    }
    __syncthreads();
    bf16x8 a[4], b[4];
#pragma unroll
    for (int mi = 0; mi < 4; mi++) a[mi] = *(const bf16x8*)(&Al[(wm + mi * 16 + lr) * 32 + lg * 8]);
#pragma unroll
    for (int ni = 0; ni < 4; ni++) b[ni] = *(const bf16x8*)(&Bl[(wn + ni * 16 + lr) * 32 + lg * 8]);
#pragma unroll
    for (int mi = 0; mi < 4; mi++)
#pragma unroll
      for (int ni = 0; ni < 4; ni++)
        acc[mi][ni] = __builtin_amdgcn_mfma_f32_16x16x32_bf16(a[mi], b[ni], acc[mi][ni], 0, 0, 0);
  }

#pragma unroll
  for (int ni = 0; ni < 4; ni++) {
    int n = bn + wn + ni * 16 + lr;
    float bv = bias[n];
#pragma unroll
    for (int mi = 0; mi < 4; mi++) {
#pragma unroll
      for (int r = 0; r < 4; r++) {
        int m = bm + wm + mi * 16 + lg * 4 + r;
        out[(size_t)m * 512 + n] = acc[mi][ni][r] + bv;
      }
    }
  }
}

// ---------------- launch ----------------

extern "C" void kernel_launch(void* const* d_in, const int* in_sizes, int n_in,
                              void* d_out, int out_size, void* d_ws, size_t ws_size,
                              hipStream_t stream) {
  const float* x = (const float*)d_in[0];
  const float* Wqkv = (const float*)d_in[1];
  const float* bqkv = (const float*)d_in[2];
  const float* Wproj = (const float*)d_in[3];
  const float* bproj = (const float*)d_in[4];
  float* out = (float*)d_out;

  char* ws = (char*)d_ws;
  short* xb  = (short*)(ws);                          // 8192*512*2      = 8388608
  short* Wqt = (short*)(ws + 8388608);                // 1536*512*2      = 1572864
  short* Wpt = (short*)(ws + 9961472);                // 512*512*2       = 524288
  short* Qb  = (short*)(ws + 10485760);               // 16*4096*64*2    = 8388608
  short* Kb  = (short*)(ws + 18874368);               // 8388608
  short* Vt  = (short*)(ws + 27262976);               // 8388608
  short* Ob  = (short*)(ws + 35651584);               // 8388608  (total 44040192)

  convert_x_kernel<<<2048, 256, 0, stream>>>(x, xb);
  transpose_w_kernel<<<192, 256, 0, stream>>>(Wqkv, Wqt, 1536, 24);
  transpose_w_kernel<<<64, 256, 0, stream>>>(Wproj, Wpt, 512, 8);
  gemm_qkv_kernel<<<768, 256, 0, stream>>>(xb, Wqt, bqkv, Qb, Kb, Vt);
  attn_kernel<<<512, 256, 0, stream>>>(Qb, Kb, Vt, Ob);
  gemm_proj_kernel<<<256, 256, 0, stream>>>(Ob, Wpt, bproj, out);
}

// Round 6
// 236.640 us; speedup vs baseline: 1.9582x; 1.0827x over previous
//
#include <hip/hip_runtime.h>
#include <hip/hip_bf16.h>
#include <stdint.h>

typedef __attribute__((ext_vector_type(8))) short bf16x8;
typedef __attribute__((ext_vector_type(4))) float f32x4;
typedef __attribute__((ext_vector_type(16))) float f32x16;
typedef __attribute__((ext_vector_type(4))) int i32x4;

__device__ __forceinline__ short f2bf(float f) {
  uint32_t u = __builtin_bit_cast(uint32_t, f);
  u = u + 0x7FFFu + ((u >> 16) & 1u);
  return (short)(u >> 16);
}

// ---------------- convert / transpose ----------------

__global__ __launch_bounds__(256) void convert_x_kernel(const float* __restrict__ x,
                                                        short* __restrict__ xb) {
  int i = (blockIdx.x * 256 + threadIdx.x) * 8;
  float4 v0 = *(const float4*)(x + i);
  float4 v1 = *(const float4*)(x + i + 4);
  uint32_t p0 = (uint16_t)f2bf(v0.x) | ((uint32_t)(uint16_t)f2bf(v0.y) << 16);
  uint32_t p1 = (uint16_t)f2bf(v0.z) | ((uint32_t)(uint16_t)f2bf(v0.w) << 16);
  uint32_t p2 = (uint16_t)f2bf(v1.x) | ((uint32_t)(uint16_t)f2bf(v1.y) << 16);
  uint32_t p3 = (uint16_t)f2bf(v1.z) | ((uint32_t)(uint16_t)f2bf(v1.w) << 16);
  i32x4 o = {(int)p0, (int)p1, (int)p2, (int)p3};
  *(i32x4*)(xb + i) = o;
}

// W [512][N] fp32 -> Wt [N][512] bf16, LDS-tiled 64x64 (coalesced both sides)
__global__ __launch_bounds__(256) void transpose_w_kernel(const float* __restrict__ W,
                                                          short* __restrict__ Wt, int N,
                                                          int nTilesN) {
  __shared__ short Ts[64 * 66];
  const int t = threadIdx.x;
  const int n0 = (blockIdx.x % nTilesN) * 64;
  const int k0 = (blockIdx.x / nTilesN) * 64;
#pragma unroll
  for (int j = 0; j < 16; j++) {
    int e = j * 256 + t;
    int k = e >> 6, n = e & 63;
    Ts[k * 66 + n] = f2bf(W[(size_t)(k0 + k) * N + n0 + n]);
  }
  __syncthreads();
#pragma unroll
  for (int j = 0; j < 16; j++) {
    int e = j * 256 + t;
    int n = e >> 6, k = e & 63;
    Wt[(size_t)(n0 + n) * 512 + k0 + k] = Ts[k * 66 + n];
  }
}

// ---------------- QKV GEMM ----------------
// A [8192][512] bf16, Bt [1536][512] bf16, out scattered to Q/K/Vt

__global__ __launch_bounds__(256) void gemm_qkv_kernel(const short* __restrict__ A,
                                                       const short* __restrict__ Bt,
                                                       const float* __restrict__ bias,
                                                       short* __restrict__ Qb,
                                                       short* __restrict__ Kb,
                                                       short* __restrict__ Vt) {
  __shared__ short Al[128 * 32];
  __shared__ short Bl[128 * 32];
  const int tid = threadIdx.x;
  const int bm = (blockIdx.x & 63) << 7;
  const int bn = (blockIdx.x >> 6) << 7;
  const int lane = tid & 63;
  const int wv = tid >> 6;
  const int wm = (wv >> 1) * 64, wn = (wv & 1) * 64;
  const int lr = lane & 15, lg = lane >> 4;

  f32x4 acc[4][4];
#pragma unroll
  for (int i = 0; i < 4; i++)
#pragma unroll
    for (int j = 0; j < 4; j++) acc[i][j] = (f32x4){0.f, 0.f, 0.f, 0.f};

  for (int k0 = 0; k0 < 512; k0 += 32) {
    __syncthreads();
#pragma unroll
    for (int i = 0; i < 2; ++i) {
      int c = tid + i * 256;
      int row = c >> 2, coff = (c & 3) * 8;
      __builtin_amdgcn_global_load_lds(
          (const __attribute__((address_space(1))) void*)(A + (size_t)(bm + row) * 512 + k0 + coff),
          (__attribute__((address_space(3))) void*)(&Al[c * 8]), 16, 0, 0);
      __builtin_amdgcn_global_load_lds(
          (const __attribute__((address_space(1))) void*)(Bt + (size_t)(bn + row) * 512 + k0 + coff),
          (__attribute__((address_space(3))) void*)(&Bl[c * 8]), 16, 0, 0);
    }
    __syncthreads();
    bf16x8 a[4], b[4];
#pragma unroll
    for (int mi = 0; mi < 4; mi++) a[mi] = *(const bf16x8*)(&Al[(wm + mi * 16 + lr) * 32 + lg * 8]);
#pragma unroll
    for (int ni = 0; ni < 4; ni++) b[ni] = *(const bf16x8*)(&Bl[(wn + ni * 16 + lr) * 32 + lg * 8]);
#pragma unroll
    for (int mi = 0; mi < 4; mi++)
#pragma unroll
      for (int ni = 0; ni < 4; ni++)
        acc[mi][ni] = __builtin_amdgcn_mfma_f32_16x16x32_bf16(a[mi], b[ni], acc[mi][ni], 0, 0, 0);
  }

#pragma unroll
  for (int ni = 0; ni < 4; ni++) {
    int n = bn + wn + ni * 16 + lr;
    float bv = bias[n];
    int three = n >> 9, hn = n & 511;
    int h = hn >> 6, d = hn & 63;
#pragma unroll
    for (int mi = 0; mi < 4; mi++) {
#pragma unroll
      for (int r = 0; r < 4; r++) {
        int m = bm + wm + mi * 16 + lg * 4 + r;
        int bb = m >> 12, s = m & 4095;
        float v = acc[mi][ni][r] + bv;
        int bh = bb * 8 + h;
        if (three == 0) {
          Qb[((size_t)bh * 4096 + s) * 64 + d] = f2bf(v * 0.125f);  // exact pre-scale
        } else if (three == 1) {
          Kb[((size_t)bh * 4096 + s) * 64 + d] = f2bf(v);
        } else {
          Vt[((size_t)bh * 64 + d) * 4096 + s] = f2bf(v);
        }
      }
    }
  }
}

// ---------------- flash attention ----------------
// Qb/Kb [bh][4096][64] bf16 (Q pre-scaled), Vt [bh][64][4096] bf16
// Ob [8192][512] bf16 (col = h*64+d)
// 32x32x16 MFMA, swapped QK^T, P in registers (T12).
// 8 waves: wave pair (w, w+4) shares q-tile w, splits keys in half (grp),
// flash-merge at end. Swizzle pos = chunk ^ (row&7) ^ ((row>>3)&3).

__global__ __launch_bounds__(512, 4) void attn_kernel(const short* __restrict__ Qb,
                                                      const short* __restrict__ Kb,
                                                      const short* __restrict__ Vt,
                                                      short* __restrict__ Ob) {
  __shared__ short Kl[2][2][64 * 64];  // [grp][buf]
  __shared__ short Vl[2][2][64 * 64];
  __shared__ float Ml[2][4][64];       // per-group m exchange
  __shared__ float Ll[4][64];          // hi-group scaled l

  const int tid = threadIdx.x;
  const int lane = tid & 63;
  const int wv = tid >> 6;   // 0..7
  const int wg = wv & 3;     // q-tile within block
  const int grp = wv >> 2;   // key half
  const int q5 = lane & 31, h = lane >> 5;
  // XCD swizzle: head pair (hh, hh+8) on XCD hh.
  const int b = blockIdx.x;
  const int qt = (b >> 3) & 31;
  const int bh = (b & 7) | ((b >> 8) << 3);

  const int qrow = qt * 128 + wg * 32 + q5;
  const short* Qrow = Qb + ((size_t)bh * 4096 + qrow) * 64;
  bf16x8 qf[4];
#pragma unroll
  for (int c = 0; c < 4; c++) qf[c] = *(const bf16x8*)(Qrow + c * 16 + h * 8);

  float m_run = -1e30f, l_run = 0.f;
  f32x16 oA, oB;
#pragma unroll
  for (int r = 0; r < 16; r++) { oA[r] = 0.f; oB[r] = 0.f; }

  const size_t kgbase = (size_t)bh * 4096 * 64 + (size_t)grp * 2048 * 64;
  const size_t vgbase = (size_t)bh * 64 * 4096 + (size_t)grp * 2048;

  // staging: per group, 4 waves cover 64 rows x 128B for K and V.
  const int srow = lane >> 3;
  const int li0 = wg * 2;

  auto stage = [&](int buf, int kb_) {
#pragma unroll
    for (int i = 0; i < 2; i++) {
      const int li = li0 + i;
      const int row = li * 8 + srow;
      const int schunk = (((lane & 7) ^ srow ^ (li & 3)) << 3);
      __builtin_amdgcn_global_load_lds(
          (const __attribute__((address_space(1))) void*)(Kb + kgbase + (size_t)(kb_ + row) * 64 + schunk),
          (__attribute__((address_space(3))) void*)(&Kl[grp][buf][li * 512]), 16, 0, 0);
      __builtin_amdgcn_global_load_lds(
          (const __attribute__((address_space(1))) void*)(Vt + vgbase + (size_t)row * 4096 + kb_ + schunk),
          (__attribute__((address_space(3))) void*)(&Vl[grp][buf][li * 512]), 16, 0, 0);
    }
  };

  stage(0, 0);
  __syncthreads();
  int cur = 0;

  const int rsw = (((q5 & 7) ^ (q5 >> 3)) << 4);  // read-side swizzle (bytes)

  for (int kb = 0; kb < 2048; kb += 64) {
    if (kb + 64 < 2048) stage(cur ^ 1, kb + 64);
    const short* Kc = &Kl[grp][cur][0];
    const short* Vc = &Vl[grp][cur][0];

#pragma unroll
    for (int ks = 0; ks < 2; ks++) {
      // ---- S^T = K @ Q^T : D[key][q]; lane holds q-row q5 scores
      f32x16 sc;
#pragma unroll
      for (int r = 0; r < 16; r++) sc[r] = 0.f;
      {
        const char* kbase = (const char*)Kc + (ks * 32 + q5) * 128;
#pragma unroll
        for (int c = 0; c < 4; c++) {
          bf16x8 kf = *(const bf16x8*)(kbase + ((((c << 1) + h) << 4) ^ rsw));
          sc = __builtin_amdgcn_mfma_f32_32x32x16_bf16(kf, qf[c], sc, 0, 0, 0);
        }
      }

      // ---- per-row max
      float pm = sc[0];
#pragma unroll
      for (int r = 1; r < 16; r++) pm = fmaxf(pm, sc[r]);
      pm = fmaxf(pm, __shfl_xor(pm, 32, 64));

      // ---- deferred rescale
      if (!__all(pm <= m_run + 8.0f)) {
        float nm = fmaxf(m_run, pm);
        float fac = exp2f((m_run - nm) * 1.44269504f);
        m_run = nm;
        l_run *= fac;
#pragma unroll
        for (int r = 0; r < 16; r++) {
          const int qm = (r & 3) + 8 * (r >> 2);
          float fr = __shfl(fac, qm + (h << 2), 64);
          oA[r] *= fr;
          oB[r] *= fr;
        }
      }

      // ---- P = exp(S - m), row-sum in f32
      const float mb = m_run * 1.44269504f;
      float p[16];
      float ls = 0.f;
#pragma unroll
      for (int r = 0; r < 16; r++) {
        p[r] = exp2f(__builtin_fmaf(sc[r], 1.44269504f, -mb));
        ls += p[r];
      }
      ls += __shfl_xor(ls, 32, 64);
      l_run += ls;

      // ---- pack P to bf16 pairs, exchange halves -> A-frags (T12)
      uint32_t w0, w1, w2, w3, w4, w5, w6, w7;
      asm("v_cvt_pk_bf16_f32 %0, %1, %2" : "=v"(w0) : "v"(p[0]), "v"(p[1]));
      asm("v_cvt_pk_bf16_f32 %0, %1, %2" : "=v"(w1) : "v"(p[2]), "v"(p[3]));
      asm("v_cvt_pk_bf16_f32 %0, %1, %2" : "=v"(w2) : "v"(p[4]), "v"(p[5]));
      asm("v_cvt_pk_bf16_f32 %0, %1, %2" : "=v"(w3) : "v"(p[6]), "v"(p[7]));
      asm("v_cvt_pk_bf16_f32 %0, %1, %2" : "=v"(w4) : "v"(p[8]), "v"(p[9]));
      asm("v_cvt_pk_bf16_f32 %0, %1, %2" : "=v"(w5) : "v"(p[10]), "v"(p[11]));
      asm("v_cvt_pk_bf16_f32 %0, %1, %2" : "=v"(w6) : "v"(p[12]), "v"(p[13]));
      asm("v_cvt_pk_bf16_f32 %0, %1, %2" : "=v"(w7) : "v"(p[14]), "v"(p[15]));
      uint32_t e0 = (uint32_t)__shfl_xor((int)(h ? w0 : w2), 32, 64);
      uint32_t e1 = (uint32_t)__shfl_xor((int)(h ? w1 : w3), 32, 64);
      uint32_t e2 = (uint32_t)__shfl_xor((int)(h ? w4 : w6), 32, 64);
      uint32_t e3 = (uint32_t)__shfl_xor((int)(h ? w5 : w7), 32, 64);
      i32x4 fa0 = {(int)(h ? e0 : w0), (int)(h ? e1 : w1), (int)(h ? w2 : e0), (int)(h ? w3 : e1)};
      i32x4 fa1 = {(int)(h ? e2 : w4), (int)(h ? e3 : w5), (int)(h ? w6 : e2), (int)(h ? w7 : e3)};
      bf16x8 pa0 = __builtin_bit_cast(bf16x8, fa0);
      bf16x8 pa1 = __builtin_bit_cast(bf16x8, fa1);

      // ---- O += P @ V
      {
        const char* vb0 = (const char*)Vc + q5 * 128;
        const char* vb1 = vb0 + 32 * 128;
        const int c0 = (((ks * 4 + h) << 4)) ^ rsw;
        const int c1 = (((ks * 4 + 2 + h) << 4)) ^ rsw;
        bf16x8 va00 = *(const bf16x8*)(vb0 + c0);
        bf16x8 va01 = *(const bf16x8*)(vb0 + c1);
        bf16x8 va10 = *(const bf16x8*)(vb1 + c0);
        bf16x8 va11 = *(const bf16x8*)(vb1 + c1);
        oA = __builtin_amdgcn_mfma_f32_32x32x16_bf16(pa0, va00, oA, 0, 0, 0);
        oA = __builtin_amdgcn_mfma_f32_32x32x16_bf16(pa1, va01, oA, 0, 0, 0);
        oB = __builtin_amdgcn_mfma_f32_32x32x16_bf16(pa0, va10, oB, 0, 0, 0);
        oB = __builtin_amdgcn_mfma_f32_32x32x16_bf16(pa1, va11, oB, 0, 0, 0);
      }
    }

    __syncthreads();  // staged loads drained + all reads of cur done
    cur ^= 1;
  }

  // ---- flash-merge of the two key halves, then store (grp 0 writes)
  Ml[grp][wg][lane] = m_run;
  __syncthreads();
  const float mp = Ml[grp ^ 1][wg][lane];
  const float M = fmaxf(m_run, mp);
  const float fac = exp2f((m_run - M) * 1.44269504f);
  const float lsc = l_run * fac;
  float* Om = (float*)&Kl[0][0][0];  // [4 wg][32 r][64 lanes] = 32KB
  if (grp == 1) {
    Ll[wg][lane] = lsc;
#pragma unroll
    for (int r = 0; r < 16; r++) {
      const int qm = (r & 3) + 8 * (r >> 2);
      float fr = __shfl(fac, qm + (h << 2), 64);
      Om[(wg * 32 + r) * 64 + lane] = oA[r] * fr;
      Om[(wg * 32 + 16 + r) * 64 + lane] = oB[r] * fr;
    }
  }
  __syncthreads();
  if (grp == 0) {
    const float l_tot = lsc + Ll[wg][lane];
    const float linv = 1.0f / l_tot;
    const int bb = bh >> 3, hh = bh & 7;
#pragma unroll
    for (int r = 0; r < 16; r++) {
      const int qm = (r & 3) + 8 * (r >> 2);
      float fr = __shfl(fac, qm + (h << 2), 64);
      float li = __shfl(linv, qm + (h << 2), 64);
      float vA = oA[r] * fr + Om[(wg * 32 + r) * 64 + lane];
      float vB = oB[r] * fr + Om[(wg * 32 + 16 + r) * 64 + lane];
      int orow = qt * 128 + wg * 32 + qm + 4 * h;
      size_t rowb = ((size_t)bb * 4096 + orow) * 512 + hh * 64;
      Ob[rowb + q5] = f2bf(vA * li);
      Ob[rowb + 32 + q5] = f2bf(vB * li);
    }
  }
}

// ---------------- proj GEMM ----------------

__global__ __launch_bounds__(256) void gemm_proj_kernel(const short* __restrict__ A,
                                                        const short* __restrict__ Bt,
                                                        const float* __restrict__ bias,
                                                        float* __restrict__ out) {
  __shared__ short Al[128 * 32];
  __shared__ short Bl[128 * 32];
  const int tid = threadIdx.x;
  const int bm = (blockIdx.x & 63) << 7;
  const int bn = (blockIdx.x >> 6) << 7;
  const int lane = tid & 63;
  const int wv = tid >> 6;
  const int wm = (wv >> 1) * 64, wn = (wv & 1) * 64;
  const int lr = lane & 15, lg = lane >> 4;

  f32x4 acc[4][4];
#pragma unroll
  for (int i = 0; i < 4; i++)
#pragma unroll
    for (int j = 0; j < 4; j++) acc[i][j] = (f32x4){0.f, 0.f, 0.f, 0.f};

  for (int k0 = 0; k0 < 512; k0 += 32) {
    __syncthreads();
#pragma unroll
    for (int i = 0; i < 2; ++i) {
      int c = tid + i * 256;
      int row = c >> 2, coff = (c & 3) * 8;
      __builtin_amdgcn_global_load_lds(
          (const __attribute__((address_space(1))) void*)(A + (size_t)(bm + row) * 512 + k0 + coff),
          (__attribute__((address_space(3))) void*)(&Al[c * 8]), 16, 0, 0);
      __builtin_amdgcn_global_load_lds(
          (const __attribute__((address_space(1))) void*)(Bt + (size_t)(bn + row) * 512 + k0 + coff),
          (__attribute__((address_space(3))) void*)(&Bl[c * 8]), 16, 0, 0);
    }
    __syncthreads();
    bf16x8 a[4], b[4];
#pragma unroll
    for (int mi = 0; mi < 4; mi++) a[mi] = *(const bf16x8*)(&Al[(wm + mi * 16 + lr) * 32 + lg * 8]);
#pragma unroll
    for (int ni = 0; ni < 4; ni++) b[ni] = *(const bf16x8*)(&Bl[(wn + ni * 16 + lr) * 32 + lg * 8]);
#pragma unroll
    for (int mi = 0; mi < 4; mi++)
#pragma unroll
      for (int ni = 0; ni < 4; ni++)
        acc[mi][ni] = __builtin_amdgcn_mfma_f32_16x16x32_bf16(a[mi], b[ni], acc[mi][ni], 0, 0, 0);
  }

#pragma unroll
  for (int ni = 0; ni < 4; ni++) {
    int n = bn + wn + ni * 16 + lr;
    float bv = bias[n];
#pragma unroll
    for (int mi = 0; mi < 4; mi++) {
#pragma unroll
      for (int r = 0; r < 4; r++) {
        int m = bm + wm + mi * 16 + lg * 4 + r;
        out[(size_t)m * 512 + n] = acc[mi][ni][r] + bv;
      }
    }
  }
}

// ---------------- launch ----------------

extern "C" void kernel_launch(void* const* d_in, const int* in_sizes, int n_in,
                              void* d_out, int out_size, void* d_ws, size_t ws_size,
                              hipStream_t stream) {
  const float* x = (const float*)d_in[0];
  const float* Wqkv = (const float*)d_in[1];
  const float* bqkv = (const float*)d_in[2];
  const float* Wproj = (const float*)d_in[3];
  const float* bproj = (const float*)d_in[4];
  float* out = (float*)d_out;

  char* ws = (char*)d_ws;
  short* xb  = (short*)(ws);                          // 8192*512*2      = 8388608
  short* Wqt = (short*)(ws + 8388608);                // 1536*512*2      = 1572864
  short* Wpt = (short*)(ws + 9961472);                // 512*512*2       = 524288
  short* Qb  = (short*)(ws + 10485760);               // 16*4096*64*2    = 8388608
  short* Kb  = (short*)(ws + 18874368);               // 8388608
  short* Vt  = (short*)(ws + 27262976);               // 8388608
  short* Ob  = (short*)(ws + 35651584);               // 8388608  (total 44040192)

  convert_x_kernel<<<2048, 256, 0, stream>>>(x, xb);
  transpose_w_kernel<<<192, 256, 0, stream>>>(Wqkv, Wqt, 1536, 24);
  transpose_w_kernel<<<64, 256, 0, stream>>>(Wproj, Wpt, 512, 8);
  gemm_qkv_kernel<<<768, 256, 0, stream>>>(xb, Wqt, bqkv, Qb, Kb, Vt);
  attn_kernel<<<512, 512, 0, stream>>>(Qb, Kb, Vt, Ob);
  gemm_proj_kernel<<<256, 256, 0, stream>>>(Ob, Wpt, bproj, out);
}

// Round 11
// 230.254 us; speedup vs baseline: 2.0125x; 1.0277x over previous
//
#include <hip/hip_runtime.h>
#include <hip/hip_bf16.h>
#include <stdint.h>

typedef __attribute__((ext_vector_type(8))) short bf16x8;
typedef __attribute__((ext_vector_type(4))) float f32x4;
typedef __attribute__((ext_vector_type(16))) float f32x16;
typedef __attribute__((ext_vector_type(4))) int i32x4;

__device__ __forceinline__ short f2bf(float f) {
  uint32_t u = __builtin_bit_cast(uint32_t, f);
  u = u + 0x7FFFu + ((u >> 16) & 1u);
  return (short)(u >> 16);
}

// ---------------- convert / transpose ----------------

__global__ __launch_bounds__(256) void convert_x_kernel(const float* __restrict__ x,
                                                        short* __restrict__ xb) {
  int i = (blockIdx.x * 256 + threadIdx.x) * 8;
  float4 v0 = *(const float4*)(x + i);
  float4 v1 = *(const float4*)(x + i + 4);
  uint32_t p0 = (uint16_t)f2bf(v0.x) | ((uint32_t)(uint16_t)f2bf(v0.y) << 16);
  uint32_t p1 = (uint16_t)f2bf(v0.z) | ((uint32_t)(uint16_t)f2bf(v0.w) << 16);
  uint32_t p2 = (uint16_t)f2bf(v1.x) | ((uint32_t)(uint16_t)f2bf(v1.y) << 16);
  uint32_t p3 = (uint16_t)f2bf(v1.z) | ((uint32_t)(uint16_t)f2bf(v1.w) << 16);
  i32x4 o = {(int)p0, (int)p1, (int)p2, (int)p3};
  *(i32x4*)(xb + i) = o;
}

// W [512][N] fp32 -> Wt [N][512] bf16, LDS-tiled 64x64 (coalesced both sides)
__global__ __launch_bounds__(256) void transpose_w_kernel(const float* __restrict__ W,
                                                          short* __restrict__ Wt, int N,
                                                          int nTilesN) {
  __shared__ short Ts[64 * 66];
  const int t = threadIdx.x;
  const int n0 = (blockIdx.x % nTilesN) * 64;
  const int k0 = (blockIdx.x / nTilesN) * 64;
#pragma unroll
  for (int j = 0; j < 16; j++) {
    int e = j * 256 + t;
    int k = e >> 6, n = e & 63;
    Ts[k * 66 + n] = f2bf(W[(size_t)(k0 + k) * N + n0 + n]);
  }
  __syncthreads();
#pragma unroll
  for (int j = 0; j < 16; j++) {
    int e = j * 256 + t;
    int n = e >> 6, k = e & 63;
    Wt[(size_t)(n0 + n) * 512 + k0 + k] = Ts[k * 66 + n];
  }
}

// ---------------- QKV GEMM ----------------
// A [8192][512] bf16, Bt [1536][512] bf16, out scattered to Q/K/Vt

__global__ __launch_bounds__(256) void gemm_qkv_kernel(const short* __restrict__ A,
                                                       const short* __restrict__ Bt,
                                                       const float* __restrict__ bias,
                                                       short* __restrict__ Qb,
                                                       short* __restrict__ Kb,
                                                       short* __restrict__ Vt) {
  __shared__ short Al[128 * 32];
  __shared__ short Bl[128 * 32];
  const int tid = threadIdx.x;
  const int bm = (blockIdx.x & 63) << 7;
  const int bn = (blockIdx.x >> 6) << 7;
  const int lane = tid & 63;
  const int wv = tid >> 6;
  const int wm = (wv >> 1) * 64, wn = (wv & 1) * 64;
  const int lr = lane & 15, lg = lane >> 4;

  f32x4 acc[4][4];
#pragma unroll
  for (int i = 0; i < 4; i++)
#pragma unroll
    for (int j = 0; j < 4; j++) acc[i][j] = (f32x4){0.f, 0.f, 0.f, 0.f};

  for (int k0 = 0; k0 < 512; k0 += 32) {
    __syncthreads();
#pragma unroll
    for (int i = 0; i < 2; ++i) {
      int c = tid + i * 256;
      int row = c >> 2, coff = (c & 3) * 8;
      __builtin_amdgcn_global_load_lds(
          (const __attribute__((address_space(1))) void*)(A + (size_t)(bm + row) * 512 + k0 + coff),
          (__attribute__((address_space(3))) void*)(&Al[c * 8]), 16, 0, 0);
      __builtin_amdgcn_global_load_lds(
          (const __attribute__((address_space(1))) void*)(Bt + (size_t)(bn + row) * 512 + k0 + coff),
          (__attribute__((address_space(3))) void*)(&Bl[c * 8]), 16, 0, 0);
    }
    __syncthreads();
    bf16x8 a[4], b[4];
#pragma unroll
    for (int mi = 0; mi < 4; mi++) a[mi] = *(const bf16x8*)(&Al[(wm + mi * 16 + lr) * 32 + lg * 8]);
#pragma unroll
    for (int ni = 0; ni < 4; ni++) b[ni] = *(const bf16x8*)(&Bl[(wn + ni * 16 + lr) * 32 + lg * 8]);
#pragma unroll
    for (int mi = 0; mi < 4; mi++)
#pragma unroll
      for (int ni = 0; ni < 4; ni++)
        acc[mi][ni] = __builtin_amdgcn_mfma_f32_16x16x32_bf16(a[mi], b[ni], acc[mi][ni], 0, 0, 0);
  }

#pragma unroll
  for (int ni = 0; ni < 4; ni++) {
    int n = bn + wn + ni * 16 + lr;
    float bv = bias[n];
    int three = n >> 9, hn = n & 511;
    int h = hn >> 6, d = hn & 63;
#pragma unroll
    for (int mi = 0; mi < 4; mi++) {
#pragma unroll
      for (int r = 0; r < 4; r++) {
        int m = bm + wm + mi * 16 + lg * 4 + r;
        int bb = m >> 12, s = m & 4095;
        float v = acc[mi][ni][r] + bv;
        int bh = bb * 8 + h;
        if (three == 0) {
          Qb[((size_t)bh * 4096 + s) * 64 + d] = f2bf(v * 0.125f);  // exact pre-scale
        } else if (three == 1) {
          Kb[((size_t)bh * 4096 + s) * 64 + d] = f2bf(v);
        } else {
          Vt[((size_t)bh * 64 + d) * 4096 + s] = f2bf(v);
        }
      }
    }
  }
}

// ---------------- flash attention ----------------
// Qb/Kb [bh][4096][64] bf16 (Q pre-scaled), Vt [bh][64][4096] bf16
// Ob [8192][512] bf16 (col = h*64+d)
// 32x32x16 MFMA, swapped QK^T, in-register softmax (shfl_xor pack — verified).
// Counted-vmcnt pipeline (T4): 2 stages in flight, raw s_barrier, vmcnt(4),
// never drain to 0 in the main loop. 8 waves = 4 q-tiles x 2 key-halves.

__global__ __launch_bounds__(512, 4) void attn_kernel(const short* __restrict__ Qb,
                                                      const short* __restrict__ Kb,
                                                      const short* __restrict__ Vt,
                                                      short* __restrict__ Ob) {
  __shared__ short Kl[2][2][64 * 64];  // [grp][buf]
  __shared__ short Vl[2][2][64 * 64];
  __shared__ float Ml[2][4][64];       // per-group m exchange
  __shared__ float Ll[4][64];          // hi-group scaled l

  const int tid = threadIdx.x;
  const int lane = tid & 63;
  const int wv = tid >> 6;   // 0..7
  const int wg = wv & 3;     // q-tile within block
  const int grp = wv >> 2;   // key half
  const int q5 = lane & 31, h = lane >> 5;
  // XCD swizzle: head pair (hh, hh+8) on XCD hh.
  const int b = blockIdx.x;
  const int qt = (b >> 3) & 31;
  const int bh = (b & 7) | ((b >> 8) << 3);

  const int qrow = qt * 128 + wg * 32 + q5;
  const short* Qrow = Qb + ((size_t)bh * 4096 + qrow) * 64;
  bf16x8 qf[4];
#pragma unroll
  for (int c = 0; c < 4; c++) qf[c] = *(const bf16x8*)(Qrow + c * 16 + h * 8);

  float m_run = -1e30f, l_run = 0.f;
  f32x16 oA, oB;
#pragma unroll
  for (int r = 0; r < 16; r++) { oA[r] = 0.f; oB[r] = 0.f; }

  const size_t kgbase = (size_t)bh * 4096 * 64 + (size_t)grp * 2048 * 64;
  const size_t vgbase = (size_t)bh * 64 * 4096 + (size_t)grp * 2048;

  // staging: per group, 4 waves cover 64 rows x 128B for K and V (4 loads/wave).
  const int srow = lane >> 3;
  const int li0 = wg * 2;

  auto stage = [&](int buf, int kb_) {
#pragma unroll
    for (int i = 0; i < 2; i++) {
      const int li = li0 + i;
      const int row = li * 8 + srow;
      const int schunk = (((lane & 7) ^ srow ^ (li & 3)) << 3);
      __builtin_amdgcn_global_load_lds(
          (const __attribute__((address_space(1))) void*)(Kb + kgbase + (size_t)(kb_ + row) * 64 + schunk),
          (__attribute__((address_space(3))) void*)(&Kl[grp][buf][li * 512]), 16, 0, 0);
      __builtin_amdgcn_global_load_lds(
          (const __attribute__((address_space(1))) void*)(Vt + vgbase + (size_t)row * 4096 + kb_ + schunk),
          (__attribute__((address_space(3))) void*)(&Vl[grp][buf][li * 512]), 16, 0, 0);
    }
  };

  stage(0, 0);
  stage(1, 64);
  int cur = 0;

  const int rsw = (((q5 & 7) ^ (q5 >> 3)) << 4);  // read-side swizzle (bytes)
  constexpr int NT = 32;  // 2048 keys / 64

  for (int t = 0; t < NT; ++t) {
    // stage(t) was issued >=1 full iteration ago; in-order vmcnt => wait for it
    if (t + 1 < NT) {
      asm volatile("s_waitcnt vmcnt(4)" ::: "memory");
    } else {
      asm volatile("s_waitcnt vmcnt(0)" ::: "memory");
    }
    __builtin_amdgcn_s_barrier();
    __builtin_amdgcn_sched_barrier(0);

    const short* Kc = &Kl[grp][cur][0];
    const short* Vc = &Vl[grp][cur][0];

#pragma unroll
    for (int ks = 0; ks < 2; ks++) {
      // ---- S^T = K @ Q^T : D[key][q]; lane holds q-row q5 scores
      f32x16 sc;
#pragma unroll
      for (int r = 0; r < 16; r++) sc[r] = 0.f;
      {
        const char* kbase = (const char*)Kc + (ks * 32 + q5) * 128;
#pragma unroll
        for (int c = 0; c < 4; c++) {
          bf16x8 kf = *(const bf16x8*)(kbase + ((((c << 1) + h) << 4) ^ rsw));
          sc = __builtin_amdgcn_mfma_f32_32x32x16_bf16(kf, qf[c], sc, 0, 0, 0);
        }
      }

      // ---- per-row max
      float pm = sc[0];
#pragma unroll
      for (int r = 1; r < 16; r++) pm = fmaxf(pm, sc[r]);
      pm = fmaxf(pm, __shfl_xor(pm, 32, 64));

      // ---- deferred rescale (wave-uniform trigger, per-lane factor)
      if (!__all(pm <= m_run + 8.0f)) {
        float nm = fmaxf(m_run, pm);
        float fac = exp2f((m_run - nm) * 1.44269504f);
        m_run = nm;
        l_run *= fac;
#pragma unroll
        for (int r = 0; r < 16; r++) {
          const int qm = (r & 3) + 8 * (r >> 2);
          float fr = __shfl(fac, qm + (h << 2), 64);
          oA[r] *= fr;
          oB[r] *= fr;
        }
      }

      // ---- P = exp(S - m), row-sum in f32
      const float mb = m_run * 1.44269504f;
      float p[16];
      float ls = 0.f;
#pragma unroll
      for (int r = 0; r < 16; r++) {
        p[r] = exp2f(__builtin_fmaf(sc[r], 1.44269504f, -mb));
        ls += p[r];
      }
      ls += __shfl_xor(ls, 32, 64);
      l_run += ls;

      // ---- pack P to bf16 pairs, exchange halves -> A-frags (verified r4-r6)
      uint32_t w0, w1, w2, w3, w4, w5, w6, w7;
      asm("v_cvt_pk_bf16_f32 %0, %1, %2" : "=v"(w0) : "v"(p[0]), "v"(p[1]));
      asm("v_cvt_pk_bf16_f32 %0, %1, %2" : "=v"(w1) : "v"(p[2]), "v"(p[3]));
      asm("v_cvt_pk_bf16_f32 %0, %1, %2" : "=v"(w2) : "v"(p[4]), "v"(p[5]));
      asm("v_cvt_pk_bf16_f32 %0, %1, %2" : "=v"(w3) : "v"(p[6]), "v"(p[7]));
      asm("v_cvt_pk_bf16_f32 %0, %1, %2" : "=v"(w4) : "v"(p[8]), "v"(p[9]));
      asm("v_cvt_pk_bf16_f32 %0, %1, %2" : "=v"(w5) : "v"(p[10]), "v"(p[11]));
      asm("v_cvt_pk_bf16_f32 %0, %1, %2" : "=v"(w6) : "v"(p[12]), "v"(p[13]));
      asm("v_cvt_pk_bf16_f32 %0, %1, %2" : "=v"(w7) : "v"(p[14]), "v"(p[15]));
      uint32_t e0 = (uint32_t)__shfl_xor((int)(h ? w0 : w2), 32, 64);
      uint32_t e1 = (uint32_t)__shfl_xor((int)(h ? w1 : w3), 32, 64);
      uint32_t e2 = (uint32_t)__shfl_xor((int)(h ? w4 : w6), 32, 64);
      uint32_t e3 = (uint32_t)__shfl_xor((int)(h ? w5 : w7), 32, 64);
      i32x4 fa0 = {(int)(h ? e0 : w0), (int)(h ? e1 : w1), (int)(h ? w2 : e0), (int)(h ? w3 : e1)};
      i32x4 fa1 = {(int)(h ? e2 : w4), (int)(h ? e3 : w5), (int)(h ? w6 : e2), (int)(h ? w7 : e3)};
      bf16x8 pa0 = __builtin_bit_cast(bf16x8, fa0);
      bf16x8 pa1 = __builtin_bit_cast(bf16x8, fa1);

      // ---- O += P @ V
      {
        const char* vb0 = (const char*)Vc + q5 * 128;
        const char* vb1 = vb0 + 32 * 128;
        const int c0 = (((ks * 4 + h) << 4)) ^ rsw;
        const int c1 = (((ks * 4 + 2 + h) << 4)) ^ rsw;
        bf16x8 va00 = *(const bf16x8*)(vb0 + c0);
        bf16x8 va01 = *(const bf16x8*)(vb0 + c1);
        bf16x8 va10 = *(const bf16x8*)(vb1 + c0);
        bf16x8 va11 = *(const bf16x8*)(vb1 + c1);
        oA = __builtin_amdgcn_mfma_f32_32x32x16_bf16(pa0, va00, oA, 0, 0, 0);
        oA = __builtin_amdgcn_mfma_f32_32x32x16_bf16(pa1, va01, oA, 0, 0, 0);
        oB = __builtin_amdgcn_mfma_f32_32x32x16_bf16(pa0, va10, oB, 0, 0, 0);
        oB = __builtin_amdgcn_mfma_f32_32x32x16_bf16(pa1, va11, oB, 0, 0, 0);
      }
    }

    __builtin_amdgcn_s_barrier();  // all reads of buf[cur] complete block-wide
    __builtin_amdgcn_sched_barrier(0);
    if (t + 2 < NT) stage(cur, (t + 2) * 64);  // overwrite just-consumed buffer
    cur ^= 1;
  }

  // ---- flash-merge of the two key halves, then store (grp 0 writes)
  Ml[grp][wg][lane] = m_run;
  __syncthreads();
  const float mp = Ml[grp ^ 1][wg][lane];
  const float M = fmaxf(m_run, mp);
  const float fac = exp2f((m_run - M) * 1.44269504f);
  const float lsc = l_run * fac;
  float* Om = (float*)&Kl[0][0][0];  // [4 wg][32 r][64 lanes] = 32KB
  if (grp == 1) {
    Ll[wg][lane] = lsc;
#pragma unroll
    for (int r = 0; r < 16; r++) {
      const int qm = (r & 3) + 8 * (r >> 2);
      float fr = __shfl(fac, qm + (h << 2), 64);
      Om[(wg * 32 + r) * 64 + lane] = oA[r] * fr;
      Om[(wg * 32 + 16 + r) * 64 + lane] = oB[r] * fr;
    }
  }
  __syncthreads();
  if (grp == 0) {
    const float l_tot = lsc + Ll[wg][lane];
    const float linv = 1.0f / l_tot;
    const int bb = bh >> 3, hh = bh & 7;
#pragma unroll
    for (int r = 0; r < 16; r++) {
      const int qm = (r & 3) + 8 * (r >> 2);
      float fr = __shfl(fac, qm + (h << 2), 64);
      float li = __shfl(linv, qm + (h << 2), 64);
      float vA = oA[r] * fr + Om[(wg * 32 + r) * 64 + lane];
      float vB = oB[r] * fr + Om[(wg * 32 + 16 + r) * 64 + lane];
      int orow = qt * 128 + wg * 32 + qm + 4 * h;
      size_t rowb = ((size_t)bb * 4096 + orow) * 512 + hh * 64;
      Ob[rowb + q5] = f2bf(vA * li);
      Ob[rowb + 32 + q5] = f2bf(vB * li);
    }
  }
}

// ---------------- proj GEMM ----------------

__global__ __launch_bounds__(256) void gemm_proj_kernel(const short* __restrict__ A,
                                                        const short* __restrict__ Bt,
                                                        const float* __restrict__ bias,
                                                        float* __restrict__ out) {
  __shared__ short Al[128 * 32];
  __shared__ short Bl[128 * 32];
  const int tid = threadIdx.x;
  const int bm = (blockIdx.x & 63) << 7;
  const int bn = (blockIdx.x >> 6) << 7;
  const int lane = tid & 63;
  const int wv = tid >> 6;
  const int wm = (wv >> 1) * 64, wn = (wv & 1) * 64;
  const int lr = lane & 15, lg = lane >> 4;

  f32x4 acc[4][4];
#pragma unroll
  for (int i = 0; i < 4; i++)
#pragma unroll
    for (int j = 0; j < 4; j++) acc[i][j] = (f32x4){0.f, 0.f, 0.f, 0.f};

  for (int k0 = 0; k0 < 512; k0 += 32) {
    __syncthreads();
#pragma unroll
    for (int i = 0; i < 2; ++i) {
      int c = tid + i * 256;
      int row = c >> 2, coff = (c & 3) * 8;
      __builtin_amdgcn_global_load_lds(
          (const __attribute__((address_space(1))) void*)(A + (size_t)(bm + row) * 512 + k0 + coff),
          (__attribute__((address_space(3))) void*)(&Al[c * 8]), 16, 0, 0);
      __builtin_amdgcn_global_load_lds(
          (const __attribute__((address_space(1))) void*)(Bt + (size_t)(bn + row) * 512 + k0 + coff),
          (__attribute__((address_space(3))) void*)(&Bl[c * 8]), 16, 0, 0);
    }
    __syncthreads();
    bf16x8 a[4], b[4];
#pragma unroll
    for (int mi = 0; mi < 4; mi++) a[mi] = *(const bf16x8*)(&Al[(wm + mi * 16 + lr) * 32 + lg * 8]);
#pragma unroll
    for (int ni = 0; ni < 4; ni++) b[ni] = *(const bf16x8*)(&Bl[(wn + ni * 16 + lr) * 32 + lg * 8]);
#pragma unroll
    for (int mi = 0; mi < 4; mi++)
#pragma unroll
      for (int ni = 0; ni < 4; ni++)
        acc[mi][ni] = __builtin_amdgcn_mfma_f32_16x16x32_bf16(a[mi], b[ni], acc[mi][ni], 0, 0, 0);
  }

#pragma unroll
  for (int ni = 0; ni < 4; ni++) {
    int n = bn + wn + ni * 16 + lr;
    float bv = bias[n];
#pragma unroll
    for (int mi = 0; mi < 4; mi++) {
#pragma unroll
      for (int r = 0; r < 4; r++) {
        int m = bm + wm + mi * 16 + lg * 4 + r;
        out[(size_t)m * 512 + n] = acc[mi][ni][r] + bv;
      }
    }
  }
}

// ---------------- launch ----------------

extern "C" void kernel_launch(void* const* d_in, const int* in_sizes, int n_in,
                              void* d_out, int out_size, void* d_ws, size_t ws_size,
                              hipStream_t stream) {
  const float* x = (const float*)d_in[0];
  const float* Wqkv = (const float*)d_in[1];
  const float* bqkv = (const float*)d_in[2];
  const float* Wproj = (const float*)d_in[3];
  const float* bproj = (const float*)d_in[4];
  float* out = (float*)d_out;

  char* ws = (char*)d_ws;
  short* xb  = (short*)(ws);                          // 8192*512*2      = 8388608
  short* Wqt = (short*)(ws + 8388608);                // 1536*512*2      = 1572864
  short* Wpt = (short*)(ws + 9961472);                // 512*512*2       = 524288
  short* Qb  = (short*)(ws + 10485760);               // 16*4096*64*2    = 8388608
  short* Kb  = (short*)(ws + 18874368);               // 8388608
  short* Vt  = (short*)(ws + 27262976);               // 8388608
  short* Ob  = (short*)(ws + 35651584);               // 8388608  (total 44040192)

  convert_x_kernel<<<2048, 256, 0, stream>>>(x, xb);
  transpose_w_kernel<<<192, 256, 0, stream>>>(Wqkv, Wqt, 1536, 24);
  transpose_w_kernel<<<64, 256, 0, stream>>>(Wproj, Wpt, 512, 8);
  gemm_qkv_kernel<<<768, 256, 0, stream>>>(xb, Wqt, bqkv, Qb, Kb, Vt);
  attn_kernel<<<512, 512, 0, stream>>>(Qb, Kb, Vt, Ob);
  gemm_proj_kernel<<<256, 256, 0, stream>>>(Ob, Wpt, bproj, out);
}